// Round 1
// 896.462 us; speedup vs baseline: 1.0155x; 1.0155x over previous
//
#include <hip/hip_runtime.h>
#include <stdint.h>

// ---------------------------------------------------------------------------
// SelfConnectionIntro: out[z,w,k] = alpha_l * sum_{u,v} x_l[z,u,k]*o[z,v]*W_l[u,v,w]
// Per path as GEMM: C[(z,k), w] = A[(z,k), u*16+v] * B[u*16+v, w]
//   A built on the fly in f16 via v_pk_mul_f16 (x * operand outer product),
//   B = W as f16, stored tile-major pre-XOR-swizzled so global_load_lds DMA
//   lands the swizzled LDS image directly (guide rule #21).
// Schedule: BK=64, double-buffered LDS, ONE barrier per K-step (2-phase):
//   stage(t+1) [A-build VALU + B-DMA] -> compute(t) -> barrier (drains vmcnt).
// ---------------------------------------------------------------------------

typedef __attribute__((ext_vector_type(8))) _Float16 f16x8;  // 4 VGPR MFMA frag
typedef __attribute__((ext_vector_type(2))) _Float16 f16x2;  // v_pk_mul_f16 pair
typedef __attribute__((ext_vector_type(4))) float f32x4;

// --- prep: f16(W) in tile-major, XOR-swizzled layout ------------------------
// For path with BN outputs: element (kk, n) -> wt[base + (t*BN + n)*64 + (c ^ ((n&7)*8))]
// where t = kk/64, c = kk%64.  GEMM DMAs 1KB chunks linearly per K-tile.
__global__ void prep_wt(const float* __restrict__ w0, const float* __restrict__ w1,
                        const float* __restrict__ w2, unsigned short* __restrict__ wt) {
    int i = blockIdx.x * 256 + threadIdx.x;
    int n, kk, BN, base;
    float v;
    if (i < 262144) {                               // path0: K=2048, BN=128
        base = 0;      n = i >> 11; kk = i & 2047; BN = 128;
        v = w0[kk * 128 + n];
    } else if (i < 327680) {                        // path1: K=1024, BN=64
        int r = i - 262144;
        base = 262144; n = r >> 10; kk = r & 1023; BN = 64;
        v = w1[kk * 64 + n];
    } else {                                        // path2: K=512, BN=32
        int r = i - 327680;
        base = 327680; n = r >> 9;  kk = r & 511;  BN = 32;
        v = w2[kk * 32 + n];
    }
    int t = kk >> 6, c = kk & 63;
    union { _Float16 h; unsigned short s; } u;
    u.h = (_Float16)v;
    wt[base + (t * BN + n) * 64 + (c ^ ((n & 7) * 8))] = u.s;
}

__device__ __forceinline__ void gl_lds16(const void* g, void* l) {
    __builtin_amdgcn_global_load_lds(
        (const __attribute__((address_space(1))) unsigned int*)g,
        (__attribute__((address_space(3))) unsigned int*)l, 16, 0, 0);
}

// --- main GEMM per path ------------------------------------------------------
// D = 2l+1, OFF = slice offset (same for in/out), K = U*16, BN = N = mul_out.
template<int D, int OFF, int K, int BN, int BM, int WAVES_M, int WAVES_N>
__global__ __launch_bounds__(256, 2)
void fctp_gemm(const float* __restrict__ x, const float* __restrict__ op,
               const unsigned short* __restrict__ wt, float* __restrict__ out,
               int Z, float alpha)
{
    constexpr int BK    = 64;                 // 4 u-values * 16 v per step
    constexpr int NSTEP = K / BK;
    constexpr int WTM   = BM / WAVES_M;
    constexpr int WTN   = BN / WAVES_N;
    constexpr int TM    = WTM / 16;
    constexpr int TN    = WTN / 16;
    constexpr int CPW   = BN / 32;            // 1KB B-DMA chunks per wave
    constexpr int NXL   = (BM == 128) ? 2 : 4; // x floats staged per thread/tile

    __shared__ unsigned short Asm_[2][BM * 64];
    __shared__ unsigned short Bsm_[2][BN * 64];

    const int tid = threadIdx.x;
    const int M   = Z * D;
    const long m0 = (long)blockIdx.x * BM;

    // A-build ownership: BM==128 -> 2 threads/row (2 u each); BM==256 -> 1 thread/row (4 u)
    int arow, usel;
    if constexpr (BM == 128) { arow = tid & 127; usel = tid >> 7; }
    else                     { arow = tid;       usel = 0;        }

    long mr = m0 + arow;
    if (mr >= M) mr = M - 1;                  // clamp (stores are guarded)
    const int zr = (int)(mr / D);
    const int kr = (int)(mr % D);

    // operand row -> 8 packed f16 pairs, lives in registers for the whole K loop
    f16x2 oh[8];
    #pragma unroll
    for (int j = 0; j < 8; ++j) {
        float a = op[(size_t)zr * 16 + 2 * j];
        float b = op[(size_t)zr * 16 + 2 * j + 1];
        oh[j] = f16x2{(_Float16)a, (_Float16)b};
    }

    // x pointer: x[z, OFF + u*D + k]; tile tt covers u = tt*4 .. tt*4+3
    const float* xbase = x + (size_t)zr * 480 + OFF + kr;
    if constexpr (BM == 128) xbase += usel * 2 * D;

    const int lane = tid & 63;
    const int wv   = tid >> 6;
    const int wm0  = (wv / WAVES_N) * WTM;
    const int wn0  = (wv % WAVES_N) * WTN;
    const int q    = lane >> 4;
    const int l16  = lane & 15;

    f32x4 acc[TM][TN];
    #pragma unroll
    for (int i = 0; i < TM; ++i)
        #pragma unroll
        for (int j = 0; j < TN; ++j) acc[i][j] = f32x4{0.f, 0.f, 0.f, 0.f};

    float xr[NXL];                            // prefetched x for the tile being staged

    auto xload = [&](int tt) {
        #pragma unroll
        for (int u = 0; u < NXL; ++u) xr[u] = xbase[(size_t)tt * 4 * D + u * D];
    };

    auto buildA = [&](int buf) {
        unsigned short* rowp = &Asm_[buf][arow * 64];
        const int swz = (arow & 7) * 8;
        #pragma unroll
        for (int u = 0; u < NXL; ++u) {
            _Float16 xh = (_Float16)xr[u];
            f16x2 xb2{xh, xh};
            unsigned int pk[8];
            #pragma unroll
            for (int j = 0; j < 8; ++j) {
                f16x2 p = xb2 * oh[j];        // v_pk_mul_f16: 2 products/instr
                pk[j] = __builtin_bit_cast(unsigned int, p);
            }
            const int cbase = (BM == 128 ? usel * 32 : 0) + u * 16;
            *(uint4*)(rowp + ((cbase    ) ^ swz)) = uint4{pk[0], pk[1], pk[2], pk[3]};
            *(uint4*)(rowp + ((cbase + 8) ^ swz)) = uint4{pk[4], pk[5], pk[6], pk[7]};
        }
    };

    auto dmaB = [&](int buf, int tt) {
        const unsigned short* src = wt + (size_t)tt * BN * 64;  // pre-swizzled tile
        unsigned short* dst = &Bsm_[buf][0];
        #pragma unroll
        for (int c = 0; c < CPW; ++c) {
            int off = (wv * CPW + c) * 512 + lane * 8;          // shorts
            gl_lds16(src + off, dst + off);
        }
    };

    auto compute = [&](int buf) {
        #pragma unroll
        for (int h = 0; h < 2; ++h) {
            f16x8 af[TM], bfr[TN];
            #pragma unroll
            for (int i = 0; i < TM; ++i) {
                int row = wm0 + i * 16 + l16;
                af[i] = *(const f16x8*)(&Asm_[buf][row * 64 + ((h * 32 + q * 8) ^ ((row & 7) * 8))]);
            }
            #pragma unroll
            for (int j = 0; j < TN; ++j) {
                int n = wn0 + j * 16 + l16;
                bfr[j] = *(const f16x8*)(&Bsm_[buf][n * 64 + ((h * 32 + q * 8) ^ ((n & 7) * 8))]);
            }
            #pragma unroll
            for (int i = 0; i < TM; ++i)
                #pragma unroll
                for (int j = 0; j < TN; ++j)
                    acc[i][j] = __builtin_amdgcn_mfma_f32_16x16x32_f16(
                        af[i], bfr[j], acc[i][j], 0, 0, 0);
        }
    };

    // ---- prologue: stage tile 0, prefetch x for tile 1 ----
    xload(0);
    dmaB(0, 0);
    buildA(0);
    xload(1);
    __syncthreads();   // vmcnt(0)+lgkmcnt(0) drain: tile 0 resident

    // ---- main loop: ONE barrier per K-step; DMA(t+1) flies under MFMA(t) ----
    for (int t = 0; t < NSTEP; ++t) {
        if (t + 1 < NSTEP) {
            int nb = (t + 1) & 1;
            dmaB(nb, t + 1);                  // issue B DMA early
            buildA(nb);                       // VALU pack of A(t+1)
            xload(t + 2 < NSTEP ? t + 2 : NSTEP - 1);  // prefetch x(t+2)
        }
        compute(t & 1);
        if (t + 1 < NSTEP) __syncthreads();   // drains DMA + A-writes, releases buf
    }

    // ---- epilogue: C/D layout col=lane&15, row=quad*4+reg (m89-verified) ----
    #pragma unroll
    for (int i = 0; i < TM; ++i) {
        #pragma unroll
        for (int p = 0; p < 4; ++p) {
            long m = m0 + wm0 + i * 16 + q * 4 + p;
            if (m < M) {
                int z = (int)(m / D);
                int k = (int)(m % D);
                float* orow = out + (size_t)z * 480 + OFF + k;
                #pragma unroll
                for (int j = 0; j < TN; ++j) {
                    int col = wn0 + j * 16 + l16;
                    orow[(size_t)col * D] = alpha * acc[i][j][p];
                }
            }
        }
    }
}

extern "C" void kernel_launch(void* const* d_in, const int* in_sizes, int n_in,
                              void* d_out, int out_size, void* d_ws, size_t ws_size,
                              hipStream_t stream) {
    (void)n_in; (void)out_size; (void)ws_size;
    const float* x  = (const float*)d_in[0];
    const float* op = (const float*)d_in[1];
    const float* w0 = (const float*)d_in[2];
    const float* w1 = (const float*)d_in[3];
    const float* w2 = (const float*)d_in[4];
    float* out = (float*)d_out;
    const int Z = in_sizes[0] / 480;

    unsigned short* wt = (unsigned short*)d_ws;    // 344064 f16 = 688128 B
    prep_wt<<<1344, 256, 0, stream>>>(w0, w1, w2, wt);

    const unsigned short* wt0 = wt;
    const unsigned short* wt1 = wt + 262144;
    const unsigned short* wt2 = wt + 327680;

    // path0: 128x0e, D=1, K=2048, N=128;  alpha = 1/sqrt(128*16)
    {
        int M = Z, BM = 128;
        fctp_gemm<1, 0, 2048, 128, 128, 2, 2>
            <<<(M + BM - 1) / BM, 256, 0, stream>>>(x, op, wt0, out, Z, 0.02209708691f);
    }
    // path1: 64x1o, D=3, K=1024, N=64;  alpha = 1/sqrt(64*16)
    {
        int M = Z * 3, BM = 256;
        fctp_gemm<3, 128, 1024, 64, 256, 2, 2>
            <<<(M + BM - 1) / BM, 256, 0, stream>>>(x, op, wt1, out, Z, 0.03125f);
    }
    // path2: 32x2e, D=5, K=512, N=32;  alpha = 1/sqrt(32*16)
    {
        int M = Z * 5, BM = 256;
        fctp_gemm<5, 320, 512, 32, 256, 4, 1>
            <<<(M + BM - 1) / BM, 256, 0, stream>>>(x, op, wt2, out, Z, 0.04419417382f);
    }
}

// Round 3
// 868.966 us; speedup vs baseline: 1.0477x; 1.0316x over previous
//
#include <hip/hip_runtime.h>
#include <stdint.h>

// ---------------------------------------------------------------------------
// SelfConnectionIntro: out[z,w,k] = alpha_l * sum_{u,v} x_l[z,u,k]*o[z,v]*W_l[u,v,w]
// GEMM per path: C[(z,k), w] = A[(z,k), u*16+v] * B[u*16+v, w]
// KEY: A-fragments are built IN REGISTERS (never staged to LDS).
//   mfma_f32_16x16x32_f16 A-layout: lane(l16,q) holds row=l16, k=q*8+0..7.
//   k = u*16+v with window of 32 = 2u x 16v  =>  u determined by q>>1 (one x
//   scalar per lane), v = (q&1)*8 + j (8 consecutive o values, lane's fixed
//   v-half).  A-frag = 4 x v_pk_mul_f16.
// B: f16 W, tile-major pre-XOR-swizzled in workspace; global_load_lds DMA,
//   double-buffered; ONE __syncthreads per K-step (BK=64).
// All three paths fused in one dispatch (branch on blockIdx).
// ---------------------------------------------------------------------------

typedef __attribute__((ext_vector_type(8))) _Float16 f16x8;  // MFMA frag (4 VGPR)
typedef __attribute__((ext_vector_type(2))) _Float16 f16x2;  // v_pk_mul_f16 pair
typedef __attribute__((ext_vector_type(4))) float f32x4;

// --- prep: f16(W) in tile-major, XOR-swizzled layout (verified r1) ----------
// element (kk, n) -> wt[base + (t*BN + n)*64 + (c ^ ((n&7)*8))], t=kk/64, c=kk%64
__global__ void prep_wt(const float* __restrict__ w0, const float* __restrict__ w1,
                        const float* __restrict__ w2, unsigned short* __restrict__ wt) {
    int i = blockIdx.x * 256 + threadIdx.x;
    int n, kk, BN, base;
    float v;
    if (i < 262144) {                               // path0: K=2048, BN=128
        base = 0;      n = i >> 11; kk = i & 2047; BN = 128;
        v = w0[kk * 128 + n];
    } else if (i < 327680) {                        // path1: K=1024, BN=64
        int r = i - 262144;
        base = 262144; n = r >> 10; kk = r & 1023; BN = 64;
        v = w1[kk * 64 + n];
    } else {                                        // path2: K=512, BN=32
        int r = i - 327680;
        base = 327680; n = r >> 9;  kk = r & 511;  BN = 32;
        v = w2[kk * 32 + n];
    }
    int t = kk >> 6, c = kk & 63;
    union { _Float16 h; unsigned short s; } u;
    u.h = (_Float16)v;
    wt[base + (t * BN + n) * 64 + (c ^ ((n & 7) * 8))] = u.s;
}

__device__ __forceinline__ void gl_lds16(const void* g, void* l) {
    __builtin_amdgcn_global_load_lds(
        (const __attribute__((address_space(1))) unsigned int*)g,
        (__attribute__((address_space(3))) unsigned int*)l, 16, 0, 0);
}

// --- per-path GEMM, inlined into the fused kernel ---------------------------
template<int D, int OFF, int K, int BN, int BM, int WM, int WN>
__device__ __forceinline__ void path_run(int bid, const float* __restrict__ x,
        const float* __restrict__ op, const unsigned short* __restrict__ wt,
        float* __restrict__ out, int Z, float alpha, unsigned short* Bsm)
{
    constexpr int NSTEP = K / 64;              // BK = 64 (4 u x 16 v)
    constexpr int WTM = BM / WM, WTN = BN / WN;
    constexpr int TM = WTM / 16, TN = WTN / 16;
    constexpr int CPW = BN / 32;               // 1KB DMA chunks per wave (4 waves)
    constexpr int TILE = BN * 64;              // shorts per K-tile
    constexpr int XW = (D == 1) ? 4 : 2;       // x floats per fragment-row per step

    const int tid  = threadIdx.x;
    const int lane = tid & 63, wv = tid >> 6;
    const int q    = lane >> 4, l16 = lane & 15;
    const int qh   = q >> 1;                   // which u of the 2 in a k-window
    const int vh   = (q & 1) * 8;              // lane's o half
    const int wm0  = (wv / WN) * WTM, wn0 = (wv % WN) * WTN;
    const int M    = Z * D;
    const long m0  = (long)bid * BM;
    const char* xb = (const char*)x;

    // ---- per fragment-row init: x byte-offset + o regs (lane's v-half) ----
    int xoff[TM];
    f16x2 oh[TM][4];
    #pragma unroll
    for (int i = 0; i < TM; ++i) {
        long m = m0 + wm0 + i * 16 + l16;
        if (m >= M) m = M - 1;                 // clamp (stores are guarded)
        int z = (int)(m / D), kr = (int)(m % D);
        xoff[i] = z * 1920 + (OFF + kr) * 4 + (D > 1 ? qh * D * 4 : 0);
        const float* o = op + (size_t)z * 16 + vh;
        #pragma unroll
        for (int j2 = 0; j2 < 4; ++j2)
            oh[i][j2] = f16x2{(_Float16)o[2 * j2], (_Float16)o[2 * j2 + 1]};
    }

    f32x4 acc[TM][TN];
    #pragma unroll
    for (int i = 0; i < TM; ++i)
        #pragma unroll
        for (int j = 0; j < TN; ++j) acc[i][j] = f32x4{0.f, 0.f, 0.f, 0.f};

    float xr0[TM][XW], xr1[TM][XW];            // static ping-pong (rule #20)

    auto dmaB = [&](int t, int buf) {
        const unsigned short* src = wt + (size_t)t * TILE;   // pre-swizzled tile
        unsigned short* dst = Bsm + buf * TILE;
        #pragma unroll
        for (int c = 0; c < CPW; ++c) {
            int off = (wv * CPW + c) * 512 + lane * 8;
            gl_lds16(src + off, dst + off);
        }
    };
    auto xloadA = [&](int t) {
        #pragma unroll
        for (int i = 0; i < TM; ++i) {
            if constexpr (D == 1) {            // 4 u's = one aligned float4
                f32x4 xv = *(const f32x4*)(xb + xoff[i] + t * 16);
                xr0[i][0] = xv[0]; xr0[i][1] = xv[1]; xr0[i][2] = xv[2]; xr0[i][3] = xv[3];
            } else {                           // u = t*4 + h*2 (+qh folded in xoff)
                xr0[i][0] = *(const float*)(xb + xoff[i] + (t * 4    ) * D * 4);
                xr0[i][1] = *(const float*)(xb + xoff[i] + (t * 4 + 2) * D * 4);
            }
        }
    };
    auto xloadB = [&](int t) {
        #pragma unroll
        for (int i = 0; i < TM; ++i) {
            if constexpr (D == 1) {
                f32x4 xv = *(const f32x4*)(xb + xoff[i] + t * 16);
                xr1[i][0] = xv[0]; xr1[i][1] = xv[1]; xr1[i][2] = xv[2]; xr1[i][3] = xv[3];
            } else {
                xr1[i][0] = *(const float*)(xb + xoff[i] + (t * 4    ) * D * 4);
                xr1[i][1] = *(const float*)(xb + xoff[i] + (t * 4 + 2) * D * 4);
            }
        }
    };
    auto computeA = [&](int buf) {
        const unsigned short* bb = Bsm + buf * TILE;
        #pragma unroll
        for (int h = 0; h < 2; ++h) {
            f16x8 bfr[TN];
            #pragma unroll
            for (int j = 0; j < TN; ++j) {
                int n = wn0 + j * 16 + l16;
                bfr[j] = *(const f16x8*)(bb + n * 64 + ((h * 32 + q * 8) ^ ((n & 7) * 8)));
            }
            #pragma unroll
            for (int i = 0; i < TM; ++i) {
                float xs;
                if constexpr (D == 1) xs = qh ? xr0[i][h * 2 + 1] : xr0[i][h * 2];
                else                  xs = xr0[i][h];
                _Float16 xh = (_Float16)xs;
                f16x2 xx{xh, xh};
                unsigned int pk[4];
                #pragma unroll
                for (int j2 = 0; j2 < 4; ++j2)
                    pk[j2] = __builtin_bit_cast(unsigned int, xx * oh[i][j2]);
                f16x8 af = __builtin_bit_cast(f16x8, uint4{pk[0], pk[1], pk[2], pk[3]});
                #pragma unroll
                for (int j = 0; j < TN; ++j)
                    acc[i][j] = __builtin_amdgcn_mfma_f32_16x16x32_f16(
                        af, bfr[j], acc[i][j], 0, 0, 0);
            }
        }
    };
    auto computeB = [&](int buf) {
        const unsigned short* bb = Bsm + buf * TILE;
        #pragma unroll
        for (int h = 0; h < 2; ++h) {
            f16x8 bfr[TN];
            #pragma unroll
            for (int j = 0; j < TN; ++j) {
                int n = wn0 + j * 16 + l16;
                bfr[j] = *(const f16x8*)(bb + n * 64 + ((h * 32 + q * 8) ^ ((n & 7) * 8)));
            }
            #pragma unroll
            for (int i = 0; i < TM; ++i) {
                float xs;
                if constexpr (D == 1) xs = qh ? xr1[i][h * 2 + 1] : xr1[i][h * 2];
                else                  xs = xr1[i][h];
                _Float16 xh = (_Float16)xs;
                f16x2 xx{xh, xh};
                unsigned int pk[4];
                #pragma unroll
                for (int j2 = 0; j2 < 4; ++j2)
                    pk[j2] = __builtin_bit_cast(unsigned int, xx * oh[i][j2]);
                f16x8 af = __builtin_bit_cast(f16x8, uint4{pk[0], pk[1], pk[2], pk[3]});
                #pragma unroll
                for (int j = 0; j < TN; ++j)
                    acc[i][j] = __builtin_amdgcn_mfma_f32_16x16x32_f16(
                        af, bfr[j], acc[i][j], 0, 0, 0);
            }
        }
    };

    // ---- prologue: stage tile 0 ----
    dmaB(0, 0);
    xloadA(0);
    __syncthreads();                           // tile 0 resident

    // ---- main loop: 2-unrolled, ONE barrier per K-step ----
    for (int t = 0; t < NSTEP; t += 2) {
        dmaB(t + 1, 1);                        // -> buf1 while computing buf0
        xloadB(t + 1);
        computeA(0);
        __syncthreads();                       // drains DMA(t+1); frees buf0
        if (t + 2 < NSTEP) { dmaB(t + 2, 0); xloadA(t + 2); }
        computeB(1);
        __syncthreads();                       // drains DMA(t+2); frees buf1
    }

    // ---- epilogue: C/D layout col=lane&15, row=q*4+reg (m89-verified) ----
    #pragma unroll
    for (int i = 0; i < TM; ++i) {
        #pragma unroll
        for (int p = 0; p < 4; ++p) {
            long m = m0 + wm0 + i * 16 + q * 4 + p;
            if (m < M) {
                int z = (int)(m / D), k = (int)(m % D);
                float* orow = out + (size_t)z * 480 + OFF + k;
                #pragma unroll
                for (int j = 0; j < TN; ++j) {
                    int col = wn0 + j * 16 + l16;
                    orow[(size_t)col * D] = alpha * acc[i][j][p];
                }
            }
        }
    }
}

// --- fused kernel: one dispatch, branch per block on path --------------------
__global__ __launch_bounds__(256, 3)
void fctp_fused(const float* __restrict__ x, const float* __restrict__ op,
                const unsigned short* __restrict__ wt, float* __restrict__ out,
                int Z, int nb0, int nb01) {
    __shared__ unsigned short Bsm[2 * 8192];   // 32 KiB (path0 size), shared by all
    int bid = blockIdx.x;
    if (bid < nb0)
        path_run<1, 0, 2048, 128, 128, 2, 2>(bid, x, op, wt, out, Z,
                                             0.02209708691f, Bsm);
    else if (bid < nb01)
        path_run<3, 128, 1024, 64, 256, 4, 1>(bid - nb0, x, op, wt + 262144, out, Z,
                                              0.03125f, Bsm);
    else
        path_run<5, 320, 512, 32, 256, 4, 1>(bid - nb01, x, op, wt + 327680, out, Z,
                                             0.04419417382f, Bsm);
}

extern "C" void kernel_launch(void* const* d_in, const int* in_sizes, int n_in,
                              void* d_out, int out_size, void* d_ws, size_t ws_size,
                              hipStream_t stream) {
    (void)n_in; (void)out_size; (void)ws_size;
    const float* x  = (const float*)d_in[0];
    const float* op = (const float*)d_in[1];
    const float* w0 = (const float*)d_in[2];
    const float* w1 = (const float*)d_in[3];
    const float* w2 = (const float*)d_in[4];
    float* out = (float*)d_out;
    const int Z = in_sizes[0] / 480;

    unsigned short* wt = (unsigned short*)d_ws;    // 344064 f16 = 688128 B
    prep_wt<<<1344, 256, 0, stream>>>(w0, w1, w2, wt);

    const int nb0 = (Z + 127) / 128;               // path0: D=1, BM=128
    const int nb1 = (3 * Z + 255) / 256;           // path1: D=3, BM=256
    const int nb2 = (5 * Z + 255) / 256;           // path2: D=5, BM=256
    fctp_fused<<<nb0 + nb1 + nb2, 256, 0, stream>>>(x, op, wt, out, Z, nb0, nb0 + nb1);
}